// Round 5
// baseline (4417.649 us; speedup 1.0000x reference)
//
#include <hip/hip_runtime.h>
#include <hip/hip_bf16.h>
#include <stdint.h>

#define HIDDEN 1024
#define FEAT   64
#define BATCH  512
#define SEQ    64
#define GATES  3072        // 3*HIDDEN

typedef __attribute__((ext_vector_type(4))) float f32x4;
typedef __attribute__((ext_vector_type(8))) short s16x8;   // 8 bf16 = 4 VGPRs (MFMA A/B frag)

__device__ inline unsigned short f2bf(float f) {
    unsigned u = __builtin_bit_cast(unsigned, f);
    u += 0x7fff + ((u >> 16) & 1);          // round-to-nearest-even
    return (unsigned short)(u >> 16);
}
__device__ inline float bf2f(unsigned short s) {
    unsigned u = ((unsigned)s) << 16;
    return __builtin_bit_cast(float, u);
}

#define GLOAD_LDS16(g, l) __builtin_amdgcn_global_load_lds( \
    (const __attribute__((address_space(1))) unsigned int*)(g), \
    (__attribute__((address_space(3))) unsigned int*)(l), 16, 0, 0)

// ---------------- weight/input conversion ----------------
// (3H, 1024) fp32 -> bf16, rows permuted so unit-tile ub's 48 rows {r:16,z:16,n:16} are contiguous
__global__ void k_conv_whh(const float* __restrict__ src, unsigned short* __restrict__ dst) {
    int i = blockIdx.x * 256 + threadIdx.x;          // 3072*1024 threads
    int d = i >> 10, k = i & 1023;
    int ub = d / 48, rem = d - ub * 48;
    int g = rem >> 4, jj = rem & 15;
    int srow = g * 1024 + ub * 16 + jj;
    dst[i] = f2bf(src[(size_t)srow * 1024 + k]);
}

// (3H, 64) fp32 -> bf16, same row permutation (layer-0 Wih)
__global__ void k_conv_wih0(const float* __restrict__ src, unsigned short* __restrict__ dst) {
    int i = blockIdx.x * 256 + threadIdx.x;          // 3072*64 threads
    int d = i >> 6, k = i & 63;
    int ub = d / 48, rem = d - ub * 48;
    int g = rem >> 4, jj = rem & 15;
    int srow = g * 1024 + ub * 16 + jj;
    dst[i] = f2bf(src[(size_t)srow * 64 + k]);
}

// x (B,T,F) fp32 -> xbf (T,B,F) bf16
__global__ void k_xpose(const float* __restrict__ x, unsigned short* __restrict__ xbf) {
    int i = blockIdx.x * blockDim.x + threadIdx.x;
    if (i >= BATCH * SEQ * FEAT) return;
    int f = i & 63, t = (i >> 6) & 63, b = i >> 12;
    xbf[((size_t)t * BATCH + b) * FEAT + f] = f2bf(x[i]);
}

// ---------------- one GEMM pass of a GRU stage ----------------
// Computes acc[i][{0,1,NSLOT}] += A(512 x K) @ B_slab(48 x K)^T for this wave's 64 rows.
// RSH: log2(B-slab row stride bytes) — 11 for K=1024, 7 for K=64. KS = K/32.
// B slab staged into LDS XOR-swizzled (pre-swizzled global source, rule #21 both-sides).
template<int RSH, int KS, int NSLOT>
__device__ __forceinline__ void gru_pass(
    const char* aBase,                       // A base (row 0, this timestep), bf16 rows
    const unsigned short* __restrict__ slabG,// pre-permuted global slab (48 rows x K)
    int groups,                              // slab bytes / 1024
    unsigned short* BsL,                     // LDS destination
    int wid, int lane, f32x4 (&acc)[4][4])
{
    constexpr int SA = (RSH == 7) ? 128 : 2048;   // A row stride, bytes
    const int l15 = lane & 15, hi = lane >> 4;

    // ---- stage slab: 1KB groups over 8 waves; source pre-swizzled, dest linear ----
    {
        const char* slab = (const char*)slabG;
        char* lbase = (char*)BsL;
        const int laneoff = lane << 4;
        for (int g = wid; g < groups; g += 8) {
            int base = g << 10;                               // wave-uniform LDS dest
            int src = base + laneoff;
            src = src ^ ((((src) >> RSH) & 7) << 4);          // involution swizzle
            GLOAD_LDS16(slab + src, lbase + base);
        }
    }
    __syncthreads();   // staged data visible (compiler drains vmcnt before barrier)

    const char* lB = (const char*)BsL;
    const int swz = (l15 & 7) << 4;
    const char* pa = aBase + (size_t)(wid * 64 + l15) * SA + (hi << 4);

    if constexpr (KS <= 4) {
        // small-K path (layer-0 Wih, K=64)
        s16x8 av[KS][4];
#pragma unroll
        for (int ks = 0; ks < KS; ++ks)
#pragma unroll
            for (int i = 0; i < 4; ++i)
                av[ks][i] = *(const s16x8*)(pa + i * 16 * SA + ks * 64);
#pragma unroll
        for (int ks = 0; ks < KS; ++ks) {
            const int kb = ks * 64 + (hi << 4);
            s16x8 b0 = *(const s16x8*)(lB + ((((0  + l15) << RSH) + kb) ^ swz));
            s16x8 b1 = *(const s16x8*)(lB + ((((16 + l15) << RSH) + kb) ^ swz));
            s16x8 b2 = *(const s16x8*)(lB + ((((32 + l15) << RSH) + kb) ^ swz));
#pragma unroll
            for (int i = 0; i < 4; ++i) {
                acc[i][0]     = __builtin_amdgcn_mfma_f32_16x16x32_bf16(av[ks][i], b0, acc[i][0], 0, 0, 0);
                acc[i][1]     = __builtin_amdgcn_mfma_f32_16x16x32_bf16(av[ks][i], b1, acc[i][1], 0, 0, 0);
                acc[i][NSLOT] = __builtin_amdgcn_mfma_f32_16x16x32_bf16(av[ks][i], b2, acc[i][NSLOT], 0, 0, 0);
            }
        }
    } else {
        // K=1024 path: 4-deep rolling A prefetch (static ring indices after full unroll)
        s16x8 ring[4][4];
#pragma unroll
        for (int p = 0; p < 4; ++p)
#pragma unroll
            for (int i = 0; i < 4; ++i)
                ring[p][i] = *(const s16x8*)(pa + i * 16 * SA + p * 64);
#pragma unroll
        for (int ks = 0; ks < KS; ++ks) {
            s16x8 cur[4];
#pragma unroll
            for (int i = 0; i < 4; ++i) cur[i] = ring[ks & 3][i];
            if (ks + 4 < KS) {
#pragma unroll
                for (int i = 0; i < 4; ++i)
                    ring[ks & 3][i] = *(const s16x8*)(pa + i * 16 * SA + (ks + 4) * 64);
            }
            const int kb = ks * 64 + (hi << 4);
            s16x8 b0 = *(const s16x8*)(lB + ((((0  + l15) << RSH) + kb) ^ swz));
            s16x8 b1 = *(const s16x8*)(lB + ((((16 + l15) << RSH) + kb) ^ swz));
            s16x8 b2 = *(const s16x8*)(lB + ((((32 + l15) << RSH) + kb) ^ swz));
#pragma unroll
            for (int i = 0; i < 4; ++i) {
                acc[i][0]     = __builtin_amdgcn_mfma_f32_16x16x32_bf16(cur[i], b0, acc[i][0], 0, 0, 0);
                acc[i][1]     = __builtin_amdgcn_mfma_f32_16x16x32_bf16(cur[i], b1, acc[i][1], 0, 0, 0);
                acc[i][NSLOT] = __builtin_amdgcn_mfma_f32_16x16x32_bf16(cur[i], b2, acc[i][NSLOT], 0, 0, 0);
            }
        }
    }
}

// ---------------- wavefront stage kernel ----------------
// Stage d runs (L0,t=d), (L1,t=d-1), (L2,t=d-2) concurrently. 192 blocks x 512 threads:
// bid = layer*64 + ub; block owns all 512 batch rows x 16 units x 3 gates.
// Pass1: Wih @ input_t (n-part -> slot 2). Pass2: Whh @ h_{t-1} (n-part -> slot 3).
// acc slots: 0=r(sum), 1=z(sum), 2=xn, 3=hn. Gate math + h write fused in epilogue.
__global__ __launch_bounds__(512, 2) void k_stage(
    int d,
    const unsigned short* __restrict__ xbf,
    unsigned short* __restrict__ h0,
    unsigned short* __restrict__ h1,
    unsigned short* __restrict__ h2,
    const unsigned short* __restrict__ wih0R,
    const unsigned short* __restrict__ whh0R,
    const unsigned short* __restrict__ wih1R,
    const unsigned short* __restrict__ whh1R,
    const unsigned short* __restrict__ wih2R,
    const unsigned short* __restrict__ whh2R,
    const float* __restrict__ bih0, const float* __restrict__ bhh0,
    const float* __restrict__ bih1, const float* __restrict__ bhh1,
    const float* __restrict__ bih2, const float* __restrict__ bhh2)
{
    __shared__ unsigned short Bs[48 * 1024];   // 96 KB (K=1024 slabs, both passes)
    __shared__ unsigned short Xs[48 * 64];     // 6 KB (layer-0 Wih slab)
    const int bid = blockIdx.x;
    const int layer = bid >> 6;
    const int ub = bid & 63;
    const int t = d - layer;
    if (t < 0 || t >= SEQ) return;

    const int tid = threadIdx.x;
    const int wid = tid >> 6, lane = tid & 63;
    const int l15 = lane & 15, hi = lane >> 4;

    f32x4 acc[4][4];
    const f32x4 zero = {0.f, 0.f, 0.f, 0.f};
#pragma unroll
    for (int i = 0; i < 4; ++i)
#pragma unroll
        for (int s = 0; s < 4; ++s) acc[i][s] = zero;

    // ---- pass 1: Wih @ input_t ----
    if (layer == 0) {
        gru_pass<7, 2, 2>((const char*)(xbf + (size_t)t * BATCH * FEAT),
                          wih0R + (size_t)ub * 48 * 64, 6, Xs, wid, lane, acc);
    } else {
        const unsigned short* inseq = (layer == 1) ? h0 : h1;
        const unsigned short* wihR  = (layer == 1) ? wih1R : wih2R;
        gru_pass<11, 32, 2>((const char*)(inseq + (size_t)t * (BATCH * HIDDEN)),
                            wihR + (size_t)ub * 48 * 1024, 96, Bs, wid, lane, acc);
    }

    unsigned short* outseq = (layer == 0) ? h0 : ((layer == 1) ? h1 : h2);
    const unsigned short* whhR = (layer == 0) ? whh0R : ((layer == 1) ? whh1R : whh2R);

    // ---- pass 2: Whh @ h_{t-1} (skip at t=0: h=0) ----
    if (t > 0) {
        __syncthreads();   // all waves done reading pass-1 LDS before restage
        gru_pass<11, 32, 3>((const char*)(outseq + (size_t)(t - 1) * (BATCH * HIDDEN)),
                            whhR + (size_t)ub * 48 * 1024, 96, Bs, wid, lane, acc);
    }

    // ---- fused gate epilogue (each wave: its 64 rows; no barrier needed) ----
    const float* bih = (layer == 0) ? bih0 : ((layer == 1) ? bih1 : bih2);
    const float* bhh = (layer == 0) ? bhh0 : ((layer == 1) ? bhh1 : bhh2);
    const int j = ub * 16 + l15;
    const float br  = bih[j] + bhh[j];
    const float bz  = bih[HIDDEN + j] + bhh[HIDDEN + j];
    const float bxn = bih[2 * HIDDEN + j];
    const float bhn = bhh[2 * HIDDEN + j];
    const unsigned short* hprev = outseq + (size_t)((t > 0) ? (t - 1) : 0) * (BATCH * HIDDEN);
    unsigned short* hout = outseq + (size_t)t * (BATCH * HIDDEN);
#pragma unroll
    for (int i = 0; i < 4; ++i)
#pragma unroll
        for (int r = 0; r < 4; ++r) {
            int brow = wid * 64 + i * 16 + hi * 4 + r;
            size_t hidx = (size_t)brow * HIDDEN + j;
            float rg = 1.f / (1.f + __expf(-(acc[i][0][r] + br)));
            float zg = 1.f / (1.f + __expf(-(acc[i][1][r] + bz)));
            float ng = tanhf(acc[i][2][r] + bxn + rg * (acc[i][3][r] + bhn));
            float hv = (t > 0) ? bf2f(hprev[hidx]) : 0.f;
            float hnew = (1.f - zg) * ng + zg * hv;
            hout[hidx] = f2bf(hnew);
        }
}

// ---------------- batch-norm over batch (bf16 input): fold to per-unit affine ----------------
__global__ void k_bn_stats(const unsigned short* __restrict__ h, const float* __restrict__ gamma,
                           const float* __restrict__ beta, float* __restrict__ a, float* __restrict__ bb)
{
    int j = blockIdx.x * 256 + threadIdx.x;
    float s = 0.f, q = 0.f;
    for (int b = 0; b < BATCH; ++b) {
        float v = bf2f(h[(size_t)b * HIDDEN + j]);
        s += v; q += v * v;
    }
    float mu = s * (1.f / BATCH);
    float var = q * (1.f / BATCH) - mu * mu;
    float rs = rsqrtf(var + 1e-5f);
    float aj = gamma[j] * rs;
    a[j] = aj;
    bb[j] = beta[j] - mu * aj;
}

// ---------------- FC(1024->1) + sigmoid ----------------
__global__ void k_fc(const unsigned short* __restrict__ h, const float* __restrict__ a, const float* __restrict__ bb,
                     const float* __restrict__ fcW, const float* __restrict__ fcb, float* __restrict__ out)
{
    int b = blockIdx.x;
    int lane = threadIdx.x;
    float s = 0.f;
    for (int j = lane; j < HIDDEN; j += 64)
        s += (bf2f(h[(size_t)b * HIDDEN + j]) * a[j] + bb[j]) * fcW[j];
#pragma unroll
    for (int m = 32; m; m >>= 1) s += __shfl_xor(s, m, 64);
    if (lane == 0) out[b] = 1.f / (1.f + __expf(-(s + fcb[0])));
}

// ---------------- driver ----------------
extern "C" void kernel_launch(void* const* d_in, const int* in_sizes, int n_in,
                              void* d_out, int out_size, void* d_ws, size_t ws_size,
                              hipStream_t stream)
{
    const float* x = (const float*)d_in[0];
    const float* W_ih[3] = {(const float*)d_in[1], (const float*)d_in[5], (const float*)d_in[9]};
    const float* W_hh[3] = {(const float*)d_in[2], (const float*)d_in[6], (const float*)d_in[10]};
    const float* b_ih[3] = {(const float*)d_in[3], (const float*)d_in[7], (const float*)d_in[11]};
    const float* b_hh[3] = {(const float*)d_in[4], (const float*)d_in[8], (const float*)d_in[12]};
    const float* gamma = (const float*)d_in[13];
    const float* beta  = (const float*)d_in[14];
    const float* fcW   = (const float*)d_in[15];
    const float* fcb   = (const float*)d_in[16];

    char* ws = (char*)d_ws;
    size_t off = 0;
    auto alloc = [&](size_t bytes) -> void* {
        void* p = ws + off;
        off = (off + bytes + 255) & ~(size_t)255;
        return p;
    };
    unsigned short* wih0R = (unsigned short*)alloc((size_t)GATES * FEAT * 2);
    unsigned short* whh0R = (unsigned short*)alloc((size_t)GATES * HIDDEN * 2);
    unsigned short* wih1R = (unsigned short*)alloc((size_t)GATES * HIDDEN * 2);
    unsigned short* whh1R = (unsigned short*)alloc((size_t)GATES * HIDDEN * 2);
    unsigned short* wih2R = (unsigned short*)alloc((size_t)GATES * HIDDEN * 2);
    unsigned short* whh2R = (unsigned short*)alloc((size_t)GATES * HIDDEN * 2);
    unsigned short* xbf = (unsigned short*)alloc((size_t)SEQ * BATCH * FEAT * 2);
    unsigned short* h0  = (unsigned short*)alloc((size_t)SEQ * BATCH * HIDDEN * 2);
    unsigned short* h1  = (unsigned short*)alloc((size_t)SEQ * BATCH * HIDDEN * 2);
    unsigned short* h2  = (unsigned short*)alloc((size_t)SEQ * BATCH * HIDDEN * 2);
    float* abuf = (float*)alloc(HIDDEN * 4);
    float* bbuf = (float*)alloc(HIDDEN * 4);

    // weights -> bf16, permuted (stateless every call)
    k_conv_wih0<<<(GATES * FEAT) / 256, 256, 0, stream>>>(W_ih[0], wih0R);
    k_conv_whh<<<(GATES * HIDDEN) / 256, 256, 0, stream>>>(W_hh[0], whh0R);
    k_conv_whh<<<(GATES * HIDDEN) / 256, 256, 0, stream>>>(W_ih[1], wih1R);
    k_conv_whh<<<(GATES * HIDDEN) / 256, 256, 0, stream>>>(W_hh[1], whh1R);
    k_conv_whh<<<(GATES * HIDDEN) / 256, 256, 0, stream>>>(W_ih[2], wih2R);
    k_conv_whh<<<(GATES * HIDDEN) / 256, 256, 0, stream>>>(W_hh[2], whh2R);
    k_xpose<<<(BATCH * SEQ * FEAT + 255) / 256, 256, 0, stream>>>(x, xbf);

    // wavefront over (layer, t): 66 stages
    for (int d = 0; d < SEQ + 2; ++d)
        k_stage<<<192, 512, 0, stream>>>(d, xbf, h0, h1, h2,
                                         wih0R, whh0R, wih1R, whh1R, wih2R, whh2R,
                                         b_ih[0], b_hh[0], b_ih[1], b_hh[1], b_ih[2], b_hh[2]);

    const unsigned short* hlast = h2 + (size_t)(SEQ - 1) * (BATCH * HIDDEN);
    k_bn_stats<<<HIDDEN / 256, 256, 0, stream>>>(hlast, gamma, beta, abuf, bbuf);
    k_fc<<<BATCH, 64, 0, stream>>>(hlast, abuf, bbuf, fcW, fcb, (float*)d_out);
}

// Round 6
// 4299.413 us; speedup vs baseline: 1.0275x; 1.0275x over previous
//
#include <hip/hip_runtime.h>
#include <hip/hip_bf16.h>
#include <stdint.h>

#define HIDDEN 1024
#define FEAT   64
#define BATCH  512
#define SEQ    64
#define GATES  3072        // 3*HIDDEN

typedef __attribute__((ext_vector_type(4))) float f32x4;
typedef __attribute__((ext_vector_type(8))) short s16x8;   // 8 bf16 = 4 VGPRs (MFMA A/B frag)

#define MFMA16(a, b, c) __builtin_amdgcn_mfma_f32_16x16x32_bf16(a, b, c, 0, 0, 0)

__device__ inline unsigned short f2bf(float f) {
    unsigned u = __builtin_bit_cast(unsigned, f);
    u += 0x7fff + ((u >> 16) & 1);          // round-to-nearest-even
    return (unsigned short)(u >> 16);
}
__device__ inline float bf2f(unsigned short s) {
    unsigned u = ((unsigned)s) << 16;
    return __builtin_bit_cast(float, u);
}

#define GLOAD_LDS16(g, l) __builtin_amdgcn_global_load_lds( \
    (const __attribute__((address_space(1))) unsigned int*)(g), \
    (__attribute__((address_space(3))) unsigned int*)(l), 16, 0, 0)

// ---------------- weight/input conversion ----------------
// (3H, 1024) fp32 -> bf16, rows permuted so unit-tile ub's 48 rows {r:16,z:16,n:16} are contiguous
__global__ void k_conv_whh(const float* __restrict__ src, unsigned short* __restrict__ dst) {
    int i = blockIdx.x * 256 + threadIdx.x;          // 3072*1024 threads
    int d = i >> 10, k = i & 1023;
    int ub = d / 48, rem = d - ub * 48;
    int g = rem >> 4, jj = rem & 15;
    int srow = g * 1024 + ub * 16 + jj;
    dst[i] = f2bf(src[(size_t)srow * 1024 + k]);
}

// (3H, 64) fp32 -> bf16, same row permutation (layer-0 Wih)
__global__ void k_conv_wih0(const float* __restrict__ src, unsigned short* __restrict__ dst) {
    int i = blockIdx.x * 256 + threadIdx.x;          // 3072*64 threads
    int d = i >> 6, k = i & 63;
    int ub = d / 48, rem = d - ub * 48;
    int g = rem >> 4, jj = rem & 15;
    int srow = g * 1024 + ub * 16 + jj;
    dst[i] = f2bf(src[(size_t)srow * 64 + k]);
}

// x (B,T,F) fp32 -> xbf (T,B,F) bf16
__global__ void k_xpose(const float* __restrict__ x, unsigned short* __restrict__ xbf) {
    int i = blockIdx.x * blockDim.x + threadIdx.x;
    if (i >= BATCH * SEQ * FEAT) return;
    int f = i & 63, t = (i >> 6) & 63, b = i >> 12;
    xbf[((size_t)t * BATCH + b) * FEAT + f] = f2bf(x[i]);
}

// ---------------- half-slab staging: 48 rows x 512 bf16 (48 KB) ----------------
// Source rows stride 2048 B (full K=1024); dest rows stride 1024 B. XOR swizzle (row&15)<<4
// applied to the SOURCE (rule #21: linear dest, pre-swizzled src, swizzled read).
__device__ __forceinline__ void stage_half(const unsigned short* __restrict__ slabG, int khalf,
                                           unsigned short* dstL, int wid, int lane)
{
    const char* slab = (const char*)slabG;
    char* lb = (char*)dstL;
    const int laneoff = lane << 4;
#pragma unroll
    for (int g = 0; g < 3; ++g) {
        int row = wid * 3 + g;                            // 0..47, wave-uniform
        int off = laneoff ^ ((row & 15) << 4);
        GLOAD_LDS16(slab + (size_t)row * 2048 + khalf * 1024 + off, lb + (row << 10));
    }
}

// ---------------- compute one K-half (16 slices of K=32) ----------------
// pa: lane's A pointer (row (wid*32+l15), khalf + hi*16 folded in), row stride 2048 B.
// lB: 48 KB half-buffer, rows 1024 B. acc slots: 0=r, 1=z, NSLOT(2|3)=n-part.
template<int NSLOT>
__device__ __forceinline__ void compute_half(const char* pa, const char* lB,
                                             int lane, f32x4 (&acc)[2][4])
{
    const int l15 = lane & 15, hi = lane >> 4;
    const int swz = l15 << 4;
    const int kb0 = hi << 4;
    const int b0o = (l15 << 10) + kb0;
    const int b1o = ((16 + l15) << 10) + kb0;
    const int b2o = ((32 + l15) << 10) + kb0;

    s16x8 ring[4][2];
#pragma unroll
    for (int p = 0; p < 4; ++p) {
        ring[p][0] = *(const s16x8*)(pa + p * 64);
        ring[p][1] = *(const s16x8*)(pa + 16 * 2048 + p * 64);
    }
#pragma unroll
    for (int ks = 0; ks < 16; ++ks) {
        s16x8 a0 = ring[ks & 3][0], a1 = ring[ks & 3][1];
        if (ks < 12) {
            ring[ks & 3][0] = *(const s16x8*)(pa + (ks + 4) * 64);
            ring[ks & 3][1] = *(const s16x8*)(pa + 16 * 2048 + (ks + 4) * 64);
        }
        s16x8 b0 = *(const s16x8*)(lB + ((b0o + ks * 64) ^ swz));
        s16x8 b1 = *(const s16x8*)(lB + ((b1o + ks * 64) ^ swz));
        s16x8 b2 = *(const s16x8*)(lB + ((b2o + ks * 64) ^ swz));
        acc[0][0]     = MFMA16(a0, b0, acc[0][0]);
        acc[0][1]     = MFMA16(a0, b1, acc[0][1]);
        acc[0][NSLOT] = MFMA16(a0, b2, acc[0][NSLOT]);
        acc[1][0]     = MFMA16(a1, b0, acc[1][0]);
        acc[1][1]     = MFMA16(a1, b1, acc[1][1]);
        acc[1][NSLOT] = MFMA16(a1, b2, acc[1][NSLOT]);
    }
}

// ---------------- layer-0 X pass: K=64, A rows 128 B ----------------
__device__ __forceinline__ void compute_x(const char* pa, const char* lX,
                                          int lane, f32x4 (&acc)[2][4])
{
    const int l15 = lane & 15, hi = lane >> 4;
    const int swz = (l15 & 7) << 4;
    s16x8 av[2][2];
#pragma unroll
    for (int ks = 0; ks < 2; ++ks)
#pragma unroll
        for (int i = 0; i < 2; ++i)
            av[ks][i] = *(const s16x8*)(pa + i * 16 * 128 + ks * 64);
#pragma unroll
    for (int ks = 0; ks < 2; ++ks) {
        const int kb = ks * 64 + (hi << 4);
        s16x8 b0 = *(const s16x8*)(lX + ((((0  + l15) << 7) + kb) ^ swz));
        s16x8 b1 = *(const s16x8*)(lX + ((((16 + l15) << 7) + kb) ^ swz));
        s16x8 b2 = *(const s16x8*)(lX + ((((32 + l15) << 7) + kb) ^ swz));
#pragma unroll
        for (int i = 0; i < 2; ++i) {
            acc[i][0] = MFMA16(av[ks][i], b0, acc[i][0]);
            acc[i][1] = MFMA16(av[ks][i], b1, acc[i][1]);
            acc[i][2] = MFMA16(av[ks][i], b2, acc[i][2]);
        }
    }
}

// ---------------- wavefront stage kernel, v2 ----------------
// Stage d: (L0,t=d), (L1,t=d-1), (L2,t=d-2). 192 blocks x 1024 threads (16 waves).
// bid = layer*64 + ub; block owns 512 batch rows x 16 units x 3 gates; wave owns 32 rows.
// Double-buffered 48 KB half-slab staging overlaps compute. Gate math fused in epilogue.
__global__ __launch_bounds__(1024, 4) void k_stage(
    int d,
    const unsigned short* __restrict__ xbf,
    unsigned short* __restrict__ h0,
    unsigned short* __restrict__ h1,
    unsigned short* __restrict__ h2,
    const unsigned short* __restrict__ wih0R,
    const unsigned short* __restrict__ whh0R,
    const unsigned short* __restrict__ wih1R,
    const unsigned short* __restrict__ whh1R,
    const unsigned short* __restrict__ wih2R,
    const unsigned short* __restrict__ whh2R,
    const float* __restrict__ bih0, const float* __restrict__ bhh0,
    const float* __restrict__ bih1, const float* __restrict__ bhh1,
    const float* __restrict__ bih2, const float* __restrict__ bhh2)
{
    __shared__ unsigned short Bs[2][24576];    // 2 x 48 KB half-slab buffers
    __shared__ unsigned short Xs[48 * 64];     // 6 KB layer-0 Wih slab
    const int bid = blockIdx.x;
    const int layer = bid >> 6;
    const int ub = bid & 63;
    const int t = d - layer;
    if (t < 0 || t >= SEQ) return;

    const int tid = threadIdx.x;
    const int wid = tid >> 6, lane = tid & 63;
    const int l15 = lane & 15, hi = lane >> 4;

    f32x4 acc[2][4];
    const f32x4 zero = {0.f, 0.f, 0.f, 0.f};
#pragma unroll
    for (int i = 0; i < 2; ++i)
#pragma unroll
        for (int s = 0; s < 4; ++s) acc[i][s] = zero;

    unsigned short* outseq = (layer == 0) ? h0 : ((layer == 1) ? h1 : h2);
    const unsigned short* whhR = ((layer == 0) ? whh0R : ((layer == 1) ? whh1R : whh2R)) + (size_t)ub * 48 * 1024;
    const char* aP2base = (const char*)(outseq + (size_t)(t - 1) * (BATCH * HIDDEN));
    // lane's per-pass A pointers
    const int arow = wid * 32 + l15;
    const char* paP2_0 = aP2base + (size_t)arow * 2048 + (hi << 4);
    const char* paP2_1 = paP2_0 + 1024;

    if (layer == 0) {
        // ---- Ph0: stage X slab (+ whh half 0 if t>0) ----
        if (wid < 6) {
            const char* slabX = (const char*)(wih0R + (size_t)ub * 48 * 64);
            int base = wid << 10;
            int pos = base + (lane << 4);
            int row = pos >> 7;
            int off = (pos & 127) ^ ((row & 7) << 4);
            GLOAD_LDS16(slabX + row * 128 + off, (char*)Xs + base);
        }
        if (t > 0) stage_half(whhR, 0, Bs[0], wid, lane);
        __syncthreads();
        // ---- Ph1: stage whh half 1; compute X-pass + whh half 0 ----
        if (t > 0) stage_half(whhR, 1, Bs[1], wid, lane);
        {
            const char* paX = (const char*)(xbf + (size_t)t * BATCH * FEAT)
                              + (size_t)arow * 128 + (hi << 4);
            compute_x(paX, (const char*)Xs, lane, acc);
        }
        if (t > 0) {
            compute_half<3>(paP2_0, (const char*)Bs[0], lane, acc);
            __syncthreads();
            // ---- Ph2 ----
            compute_half<3>(paP2_1, (const char*)Bs[1], lane, acc);
        }
    } else {
        const unsigned short* inseq = (layer == 1) ? h0 : h1;
        const unsigned short* wihR = ((layer == 1) ? wih1R : wih2R) + (size_t)ub * 48 * 1024;
        const char* aP1base = (const char*)(inseq + (size_t)t * (BATCH * HIDDEN));
        const char* paP1_0 = aP1base + (size_t)arow * 2048 + (hi << 4);
        const char* paP1_1 = paP1_0 + 1024;
        // ---- Ph0 ----
        stage_half(wihR, 0, Bs[0], wid, lane);
        __syncthreads();
        // ---- Ph1 ----
        stage_half(wihR, 1, Bs[1], wid, lane);
        compute_half<2>(paP1_0, (const char*)Bs[0], lane, acc);
        __syncthreads();
        // ---- Ph2 ----
        if (t > 0) stage_half(whhR, 0, Bs[0], wid, lane);
        compute_half<2>(paP1_1, (const char*)Bs[1], lane, acc);
        __syncthreads();
        if (t > 0) {
            // ---- Ph3 ----
            stage_half(whhR, 1, Bs[1], wid, lane);
            compute_half<3>(paP2_0, (const char*)Bs[0], lane, acc);
            __syncthreads();
            // ---- Ph4 ----
            compute_half<3>(paP2_1, (const char*)Bs[1], lane, acc);
        }
    }

    // ---- fused gate epilogue: each wave writes its 32 rows ----
    const float* bih = (layer == 0) ? bih0 : ((layer == 1) ? bih1 : bih2);
    const float* bhh = (layer == 0) ? bhh0 : ((layer == 1) ? bhh1 : bhh2);
    const int j = ub * 16 + l15;
    const float br  = bih[j] + bhh[j];
    const float bz  = bih[HIDDEN + j] + bhh[HIDDEN + j];
    const float bxn = bih[2 * HIDDEN + j];
    const float bhn = bhh[2 * HIDDEN + j];
    const unsigned short* hprev = outseq + (size_t)((t > 0) ? (t - 1) : 0) * (BATCH * HIDDEN);
    unsigned short* hout = outseq + (size_t)t * (BATCH * HIDDEN);
#pragma unroll
    for (int i = 0; i < 2; ++i)
#pragma unroll
        for (int r = 0; r < 4; ++r) {
            int brow = wid * 32 + i * 16 + hi * 4 + r;
            size_t hidx = (size_t)brow * HIDDEN + j;
            float rg = 1.f / (1.f + __expf(-(acc[i][0][r] + br)));
            float zg = 1.f / (1.f + __expf(-(acc[i][1][r] + bz)));
            float ng = tanhf(acc[i][2][r] + bxn + rg * (acc[i][3][r] + bhn));
            float hv = (t > 0) ? bf2f(hprev[hidx]) : 0.f;
            float hnew = (1.f - zg) * ng + zg * hv;
            hout[hidx] = f2bf(hnew);
        }
}

// ---------------- batch-norm over batch: coalesced two-phase, deterministic ----------------
__global__ void k_bn_part(const unsigned short* __restrict__ h, float* __restrict__ part) {
    int j = threadIdx.x;                 // 1024 threads = all units
    int blk = blockIdx.x;                // 16 blocks x 32 rows
    float s = 0.f, q = 0.f;
    for (int b = blk * 32; b < blk * 32 + 32; ++b) {
        float v = bf2f(h[(size_t)b * HIDDEN + j]);
        s += v; q += v * v;
    }
    part[blk * 2048 + j] = s;
    part[blk * 2048 + 1024 + j] = q;
}

__global__ void k_bn_fold(const float* __restrict__ part, const float* __restrict__ gamma,
                          const float* __restrict__ beta, float* __restrict__ a, float* __restrict__ bb)
{
    int j = blockIdx.x * 256 + threadIdx.x;   // HIDDEN threads
    float s = 0.f, q = 0.f;
    for (int p = 0; p < 16; ++p) {
        s += part[p * 2048 + j];
        q += part[p * 2048 + 1024 + j];
    }
    float mu = s * (1.f / BATCH);
    float var = q * (1.f / BATCH) - mu * mu;
    float rs = rsqrtf(var + 1e-5f);
    float aj = gamma[j] * rs;
    a[j] = aj;
    bb[j] = beta[j] - mu * aj;
}

// ---------------- FC(1024->1) + sigmoid ----------------
__global__ void k_fc(const unsigned short* __restrict__ h, const float* __restrict__ a, const float* __restrict__ bb,
                     const float* __restrict__ fcW, const float* __restrict__ fcb, float* __restrict__ out)
{
    int b = blockIdx.x;
    int lane = threadIdx.x;
    float s = 0.f;
    for (int j = lane; j < HIDDEN; j += 64)
        s += (bf2f(h[(size_t)b * HIDDEN + j]) * a[j] + bb[j]) * fcW[j];
#pragma unroll
    for (int m = 32; m; m >>= 1) s += __shfl_xor(s, m, 64);
    if (lane == 0) out[b] = 1.f / (1.f + __expf(-(s + fcb[0])));
}

// ---------------- driver ----------------
extern "C" void kernel_launch(void* const* d_in, const int* in_sizes, int n_in,
                              void* d_out, int out_size, void* d_ws, size_t ws_size,
                              hipStream_t stream)
{
    const float* x = (const float*)d_in[0];
    const float* W_ih[3] = {(const float*)d_in[1], (const float*)d_in[5], (const float*)d_in[9]};
    const float* W_hh[3] = {(const float*)d_in[2], (const float*)d_in[6], (const float*)d_in[10]};
    const float* b_ih[3] = {(const float*)d_in[3], (const float*)d_in[7], (const float*)d_in[11]};
    const float* b_hh[3] = {(const float*)d_in[4], (const float*)d_in[8], (const float*)d_in[12]};
    const float* gamma = (const float*)d_in[13];
    const float* beta  = (const float*)d_in[14];
    const float* fcW   = (const float*)d_in[15];
    const float* fcb   = (const float*)d_in[16];

    char* ws = (char*)d_ws;
    size_t off = 0;
    auto alloc = [&](size_t bytes) -> void* {
        void* p = ws + off;
        off = (off + bytes + 255) & ~(size_t)255;
        return p;
    };
    unsigned short* wih0R = (unsigned short*)alloc((size_t)GATES * FEAT * 2);
    unsigned short* whh0R = (unsigned short*)alloc((size_t)GATES * HIDDEN * 2);
    unsigned short* wih1R = (unsigned short*)alloc((size_t)GATES * HIDDEN * 2);
    unsigned short* whh1R = (unsigned short*)alloc((size_t)GATES * HIDDEN * 2);
    unsigned short* wih2R = (unsigned short*)alloc((size_t)GATES * HIDDEN * 2);
    unsigned short* whh2R = (unsigned short*)alloc((size_t)GATES * HIDDEN * 2);
    unsigned short* xbf = (unsigned short*)alloc((size_t)SEQ * BATCH * FEAT * 2);
    unsigned short* h0  = (unsigned short*)alloc((size_t)SEQ * BATCH * HIDDEN * 2);
    unsigned short* h1  = (unsigned short*)alloc((size_t)SEQ * BATCH * HIDDEN * 2);
    unsigned short* h2  = (unsigned short*)alloc((size_t)SEQ * BATCH * HIDDEN * 2);
    float* part = (float*)alloc(16 * 2048 * 4);
    float* abuf = (float*)alloc(HIDDEN * 4);
    float* bbuf = (float*)alloc(HIDDEN * 4);

    // weights -> bf16, permuted (stateless every call)
    k_conv_wih0<<<(GATES * FEAT) / 256, 256, 0, stream>>>(W_ih[0], wih0R);
    k_conv_whh<<<(GATES * HIDDEN) / 256, 256, 0, stream>>>(W_hh[0], whh0R);
    k_conv_whh<<<(GATES * HIDDEN) / 256, 256, 0, stream>>>(W_ih[1], wih1R);
    k_conv_whh<<<(GATES * HIDDEN) / 256, 256, 0, stream>>>(W_hh[1], whh1R);
    k_conv_whh<<<(GATES * HIDDEN) / 256, 256, 0, stream>>>(W_ih[2], wih2R);
    k_conv_whh<<<(GATES * HIDDEN) / 256, 256, 0, stream>>>(W_hh[2], whh2R);
    k_xpose<<<(BATCH * SEQ * FEAT + 255) / 256, 256, 0, stream>>>(x, xbf);

    // wavefront over (layer, t): 66 stages
    for (int d = 0; d < SEQ + 2; ++d)
        k_stage<<<192, 1024, 0, stream>>>(d, xbf, h0, h1, h2,
                                          wih0R, whh0R, wih1R, whh1R, wih2R, whh2R,
                                          b_ih[0], b_hh[0], b_ih[1], b_hh[1], b_ih[2], b_hh[2]);

    const unsigned short* hlast = h2 + (size_t)(SEQ - 1) * (BATCH * HIDDEN);
    k_bn_part<<<16, 1024, 0, stream>>>(hlast, part);
    k_bn_fold<<<HIDDEN / 256, 256, 0, stream>>>(part, gamma, beta, abuf, bbuf);
    k_fc<<<BATCH, 64, 0, stream>>>(hlast, abuf, bbuf, fcW, fcb, (float*)d_out);
}

// Round 7
// 2286.965 us; speedup vs baseline: 1.9317x; 1.8800x over previous
//
#include <hip/hip_runtime.h>
#include <hip/hip_bf16.h>
#include <stdint.h>

#define HIDDEN 1024
#define FEAT   64
#define BATCH  512
#define SEQ    64
#define GATES  3072        // 3*HIDDEN

typedef __attribute__((ext_vector_type(4))) float f32x4;
typedef __attribute__((ext_vector_type(8))) short s16x8;   // 8 bf16 = 4 VGPRs (MFMA A/B frag)

#define MFMA16(a, b, c) __builtin_amdgcn_mfma_f32_16x16x32_bf16(a, b, c, 0, 0, 0)

__device__ inline unsigned short f2bf(float f) {
    unsigned u = __builtin_bit_cast(unsigned, f);
    u += 0x7fff + ((u >> 16) & 1);          // round-to-nearest-even
    return (unsigned short)(u >> 16);
}
__device__ inline float bf2f(unsigned short s) {
    unsigned u = ((unsigned)s) << 16;
    return __builtin_bit_cast(float, u);
}

#define GLOAD_LDS16(g, l) __builtin_amdgcn_global_load_lds( \
    (const __attribute__((address_space(1))) unsigned int*)(g), \
    (__attribute__((address_space(3))) unsigned int*)(l), 16, 0, 0)

// ---------------- weight/input conversion ----------------
// (3H, 1024) fp32 -> bf16, rows permuted so unit-tile ub's 48 rows {r:16,z:16,n:16} are contiguous
__global__ void k_conv_whh(const float* __restrict__ src, unsigned short* __restrict__ dst) {
    int i = blockIdx.x * 256 + threadIdx.x;          // 3072*1024 threads
    int d = i >> 10, k = i & 1023;
    int ub = d / 48, rem = d - ub * 48;
    int g = rem >> 4, jj = rem & 15;
    int srow = g * 1024 + ub * 16 + jj;
    dst[i] = f2bf(src[(size_t)srow * 1024 + k]);
}

// (3H, 64) fp32 -> bf16, same row permutation (layer-0 Wih)
__global__ void k_conv_wih0(const float* __restrict__ src, unsigned short* __restrict__ dst) {
    int i = blockIdx.x * 256 + threadIdx.x;          // 3072*64 threads
    int d = i >> 6, k = i & 63;
    int ub = d / 48, rem = d - ub * 48;
    int g = rem >> 4, jj = rem & 15;
    int srow = g * 1024 + ub * 16 + jj;
    dst[i] = f2bf(src[(size_t)srow * 64 + k]);
}

// x (B,T,F) fp32 -> xbf (T,B,F) bf16
__global__ void k_xpose(const float* __restrict__ x, unsigned short* __restrict__ xbf) {
    int i = blockIdx.x * blockDim.x + threadIdx.x;
    if (i >= BATCH * SEQ * FEAT) return;
    int f = i & 63, t = (i >> 6) & 63, b = i >> 12;
    xbf[((size_t)t * BATCH + b) * FEAT + f] = f2bf(x[i]);
}

// ---------------- chunk staging: n x 1KB groups, 8 rows x 128B per group ----------------
// LDS[row][col16] = src[row][col16 ^ (row&7)]  (pre-swizzled source, linear LDS dest — rule #21).
// src already includes base-row and k-chunk byte offsets; rowStride in bytes.
__device__ __forceinline__ void stage_chunk(const char* src, int rowStride,
                                            unsigned short* dstL, int nKB, int wid, int lane)
{
    const int lrow = lane >> 3;
    const int lcol = lane & 7;
    for (int g = wid; g < nKB; g += 4) {
        int row = g * 8 + lrow;
        int col16 = lcol ^ (row & 7);
        GLOAD_LDS16(src + (size_t)row * rowStride + col16 * 16, (char*)dstL + (g << 10));
    }
}

// ---------------- compute one 64-col K-chunk: 2 k-slices x 6 MFMA ----------------
// aL: 128 rows x 128B, wL: 48 rows x 128B, both XOR-swizzled. acc slots: 0=r, 1=z, NSLOT=n-part.
template<int NSLOT>
__device__ __forceinline__ void compute_chunk(const unsigned short* aL, const unsigned short* wL,
                                              int wid, int lane, f32x4 (&acc)[2][4])
{
    const int l15 = lane & 15, hi = lane >> 4;
    const int swz = (l15 & 7) << 4;
    const char* ap = (const char*)aL;
    const char* wp = (const char*)wL;
#pragma unroll
    for (int ks = 0; ks < 2; ++ks) {
        const int kb = ks * 64 + (hi << 4);
        s16x8 a0 = *(const s16x8*)(ap + ((((wid * 32 + l15) * 128) + kb) ^ swz));
        s16x8 a1 = *(const s16x8*)(ap + ((((wid * 32 + 16 + l15) * 128) + kb) ^ swz));
        s16x8 b0 = *(const s16x8*)(wp + (((l15 * 128) + kb) ^ swz));
        s16x8 b1 = *(const s16x8*)(wp + ((((16 + l15) * 128) + kb) ^ swz));
        s16x8 b2 = *(const s16x8*)(wp + ((((32 + l15) * 128) + kb) ^ swz));
        acc[0][0]     = MFMA16(a0, b0, acc[0][0]);
        acc[0][1]     = MFMA16(a0, b1, acc[0][1]);
        acc[0][NSLOT] = MFMA16(a0, b2, acc[0][NSLOT]);
        acc[1][0]     = MFMA16(a1, b0, acc[1][0]);
        acc[1][1]     = MFMA16(a1, b1, acc[1][1]);
        acc[1][NSLOT] = MFMA16(a1, b2, acc[1][NSLOT]);
    }
}

// ---------------- wavefront stage kernel, v3: all-staged, 3 blocks/CU ----------------
// Stage d: (L0,t=d), (L1,t=d-1), (L2,t=d-2). 768 blocks x 256 threads (4 waves, wave = 32 rows).
// Block: 128 batch rows x 16 units x 3 gates. K in 64-col chunks, double-buffered LDS
// (A 16KB + W 6KB per buffer), one barrier per chunk. XCD-pinned grid mapping: the 4
// batch-group blocks of one (layer,ub) share a slot mod 8 -> same XCD -> slab L2-shared.
__global__ __launch_bounds__(256, 3) void k_stage(
    int d,
    const unsigned short* __restrict__ xbf,
    unsigned short* __restrict__ h0,
    unsigned short* __restrict__ h1,
    unsigned short* __restrict__ h2,
    const unsigned short* __restrict__ wih0R,
    const unsigned short* __restrict__ whh0R,
    const unsigned short* __restrict__ wih1R,
    const unsigned short* __restrict__ whh1R,
    const unsigned short* __restrict__ wih2R,
    const unsigned short* __restrict__ whh2R,
    const float* __restrict__ bih0, const float* __restrict__ bhh0,
    const float* __restrict__ bih1, const float* __restrict__ bhh1,
    const float* __restrict__ bih2, const float* __restrict__ bhh2)
{
    __shared__ unsigned short Wb[2][48 * 64];    // 2 x 6 KB
    __shared__ unsigned short Ab[2][128 * 64];   // 2 x 16 KB
    const int bid = blockIdx.x;
    const int slot = bid & 7;
    const int p = (bid >> 3) % 24;
    const int bg = bid / 192;                    // batch group 0..3
    const int pair = slot + 8 * p;               // 0..191
    const int layer = pair >> 6;
    const int ub = pair & 63;
    const int t = d - layer;
    if (t < 0 || t >= SEQ) return;

    const int tid = threadIdx.x;
    const int wid = tid >> 6, lane = tid & 63;
    const int l15 = lane & 15, hi = lane >> 4;
    const int brow0 = bg * 128;

    const unsigned short* inseq = (layer == 0) ? xbf : ((layer == 1) ? h0 : h1);
    unsigned short* outseq = (layer == 0) ? h0 : ((layer == 1) ? h1 : h2);
    const unsigned short* wihR = (layer == 0) ? wih0R : ((layer == 1) ? wih1R : wih2R);
    const unsigned short* whhR = (layer == 0) ? whh0R : ((layer == 1) ? whh1R : whh2R);

    const int aStride1 = (layer == 0) ? 128 : 2048;           // bytes per A row, pass 1
    const char* a1base = (layer == 0)
        ? (const char*)xbf + (size_t)t * BATCH * FEAT * 2 + (size_t)brow0 * 128
        : (const char*)inseq + (size_t)t * BATCH * HIDDEN * 2 + (size_t)brow0 * 2048;
    const char* w1base = (layer == 0)
        ? (const char*)wihR + (size_t)ub * 48 * 64 * 2
        : (const char*)wihR + (size_t)ub * 48 * 1024 * 2;
    const int wStride1 = (layer == 0) ? 128 : 2048;
    const char* a2base = (const char*)outseq + (size_t)(t - 1) * BATCH * HIDDEN * 2 + (size_t)brow0 * 2048;
    const char* w2base = (const char*)whhR + (size_t)ub * 48 * 1024 * 2;

    const int NCH1 = (layer == 0) ? 1 : 16;
    const int NCH2 = (t > 0) ? 16 : 0;

    f32x4 acc[2][4];
    const f32x4 zero = {0.f, 0.f, 0.f, 0.f};
#pragma unroll
    for (int i = 0; i < 2; ++i)
#pragma unroll
        for (int s = 0; s < 4; ++s) acc[i][s] = zero;

    int cur = 0;
    // prologue: stage pass-1 chunk 0
    stage_chunk(w1base, wStride1, Wb[0], 6, wid, lane);
    stage_chunk(a1base, aStride1, Ab[0], 16, wid, lane);
    __syncthreads();

    // pass 1 (n-part -> slot 2)
    for (int c = 0; c < NCH1; ++c) {
        int nxt = cur ^ 1;
        if (c + 1 < NCH1) {
            stage_chunk(w1base + (c + 1) * 128, wStride1, Wb[nxt], 6, wid, lane);
            stage_chunk(a1base + (c + 1) * 128, aStride1, Ab[nxt], 16, wid, lane);
        } else if (NCH2 > 0) {
            stage_chunk(w2base, 2048, Wb[nxt], 6, wid, lane);
            stage_chunk(a2base, 2048, Ab[nxt], 16, wid, lane);
        }
        compute_chunk<2>(Ab[cur], Wb[cur], wid, lane, acc);
        __syncthreads();
        cur = nxt;
    }
    // pass 2 (n-part -> slot 3)
    for (int c = 0; c < NCH2; ++c) {
        int nxt = cur ^ 1;
        if (c + 1 < NCH2) {
            stage_chunk(w2base + (c + 1) * 128, 2048, Wb[nxt], 6, wid, lane);
            stage_chunk(a2base + (c + 1) * 128, 2048, Ab[nxt], 16, wid, lane);
        }
        compute_chunk<3>(Ab[cur], Wb[cur], wid, lane, acc);
        __syncthreads();
        cur = nxt;
    }

    // ---- fused gate epilogue: each wave writes its 32 rows ----
    const float* bih = (layer == 0) ? bih0 : ((layer == 1) ? bih1 : bih2);
    const float* bhh = (layer == 0) ? bhh0 : ((layer == 1) ? bhh1 : bhh2);
    const int j = ub * 16 + l15;
    const float br  = bih[j] + bhh[j];
    const float bz  = bih[HIDDEN + j] + bhh[HIDDEN + j];
    const float bxn = bih[2 * HIDDEN + j];
    const float bhn = bhh[2 * HIDDEN + j];
    const unsigned short* hprev = outseq + (size_t)((t > 0) ? (t - 1) : 0) * (BATCH * HIDDEN);
    unsigned short* hout = outseq + (size_t)t * (BATCH * HIDDEN);
#pragma unroll
    for (int i = 0; i < 2; ++i)
#pragma unroll
        for (int r = 0; r < 4; ++r) {
            int brow = brow0 + wid * 32 + i * 16 + hi * 4 + r;
            size_t hidx = (size_t)brow * HIDDEN + j;
            float rg = 1.f / (1.f + __expf(-(acc[i][0][r] + br)));
            float zg = 1.f / (1.f + __expf(-(acc[i][1][r] + bz)));
            float ng = tanhf(acc[i][2][r] + bxn + rg * (acc[i][3][r] + bhn));
            float hv = (t > 0) ? bf2f(hprev[hidx]) : 0.f;
            float hnew = (1.f - zg) * ng + zg * hv;
            hout[hidx] = f2bf(hnew);
        }
}

// ---------------- batch-norm over batch: coalesced two-phase, deterministic ----------------
__global__ void k_bn_part(const unsigned short* __restrict__ h, float* __restrict__ part) {
    int j = threadIdx.x;                 // 1024 threads = all units
    int blk = blockIdx.x;                // 16 blocks x 32 rows
    float s = 0.f, q = 0.f;
    for (int b = blk * 32; b < blk * 32 + 32; ++b) {
        float v = bf2f(h[(size_t)b * HIDDEN + j]);
        s += v; q += v * v;
    }
    part[blk * 2048 + j] = s;
    part[blk * 2048 + 1024 + j] = q;
}

__global__ void k_bn_fold(const float* __restrict__ part, const float* __restrict__ gamma,
                          const float* __restrict__ beta, float* __restrict__ a, float* __restrict__ bb)
{
    int j = blockIdx.x * 256 + threadIdx.x;   // HIDDEN threads
    float s = 0.f, q = 0.f;
    for (int p = 0; p < 16; ++p) {
        s += part[p * 2048 + j];
        q += part[p * 2048 + 1024 + j];
    }
    float mu = s * (1.f / BATCH);
    float var = q * (1.f / BATCH) - mu * mu;
    float rs = rsqrtf(var + 1e-5f);
    float aj = gamma[j] * rs;
    a[j] = aj;
    bb[j] = beta[j] - mu * aj;
}

// ---------------- FC(1024->1) + sigmoid ----------------
__global__ void k_fc(const unsigned short* __restrict__ h, const float* __restrict__ a, const float* __restrict__ bb,
                     const float* __restrict__ fcW, const float* __restrict__ fcb, float* __restrict__ out)
{
    int b = blockIdx.x;
    int lane = threadIdx.x;
    float s = 0.f;
    for (int j = lane; j < HIDDEN; j += 64)
        s += (bf2f(h[(size_t)b * HIDDEN + j]) * a[j] + bb[j]) * fcW[j];
#pragma unroll
    for (int m = 32; m; m >>= 1) s += __shfl_xor(s, m, 64);
    if (lane == 0) out[b] = 1.f / (1.f + __expf(-(s + fcb[0])));
}

// ---------------- driver ----------------
extern "C" void kernel_launch(void* const* d_in, const int* in_sizes, int n_in,
                              void* d_out, int out_size, void* d_ws, size_t ws_size,
                              hipStream_t stream)
{
    const float* x = (const float*)d_in[0];
    const float* W_ih[3] = {(const float*)d_in[1], (const float*)d_in[5], (const float*)d_in[9]};
    const float* W_hh[3] = {(const float*)d_in[2], (const float*)d_in[6], (const float*)d_in[10]};
    const float* b_ih[3] = {(const float*)d_in[3], (const float*)d_in[7], (const float*)d_in[11]};
    const float* b_hh[3] = {(const float*)d_in[4], (const float*)d_in[8], (const float*)d_in[12]};
    const float* gamma = (const float*)d_in[13];
    const float* beta  = (const float*)d_in[14];
    const float* fcW   = (const float*)d_in[15];
    const float* fcb   = (const float*)d_in[16];

    char* ws = (char*)d_ws;
    size_t off = 0;
    auto alloc = [&](size_t bytes) -> void* {
        void* p = ws + off;
        off = (off + bytes + 255) & ~(size_t)255;
        return p;
    };
    unsigned short* wih0R = (unsigned short*)alloc((size_t)GATES * FEAT * 2);
    unsigned short* whh0R = (unsigned short*)alloc((size_t)GATES * HIDDEN * 2);
    unsigned short* wih1R = (unsigned short*)alloc((size_t)GATES * HIDDEN * 2);
    unsigned short* whh1R = (unsigned short*)alloc((size_t)GATES * HIDDEN * 2);
    unsigned short* wih2R = (unsigned short*)alloc((size_t)GATES * HIDDEN * 2);
    unsigned short* whh2R = (unsigned short*)alloc((size_t)GATES * HIDDEN * 2);
    unsigned short* xbf = (unsigned short*)alloc((size_t)SEQ * BATCH * FEAT * 2);
    unsigned short* h0  = (unsigned short*)alloc((size_t)SEQ * BATCH * HIDDEN * 2);
    unsigned short* h1  = (unsigned short*)alloc((size_t)SEQ * BATCH * HIDDEN * 2);
    unsigned short* h2  = (unsigned short*)alloc((size_t)SEQ * BATCH * HIDDEN * 2);
    float* part = (float*)alloc(16 * 2048 * 4);
    float* abuf = (float*)alloc(HIDDEN * 4);
    float* bbuf = (float*)alloc(HIDDEN * 4);

    // weights -> bf16, permuted (stateless every call)
    k_conv_wih0<<<(GATES * FEAT) / 256, 256, 0, stream>>>(W_ih[0], wih0R);
    k_conv_whh<<<(GATES * HIDDEN) / 256, 256, 0, stream>>>(W_hh[0], whh0R);
    k_conv_whh<<<(GATES * HIDDEN) / 256, 256, 0, stream>>>(W_ih[1], wih1R);
    k_conv_whh<<<(GATES * HIDDEN) / 256, 256, 0, stream>>>(W_hh[1], whh1R);
    k_conv_whh<<<(GATES * HIDDEN) / 256, 256, 0, stream>>>(W_ih[2], wih2R);
    k_conv_whh<<<(GATES * HIDDEN) / 256, 256, 0, stream>>>(W_hh[2], whh2R);
    k_xpose<<<(BATCH * SEQ * FEAT + 255) / 256, 256, 0, stream>>>(x, xbf);

    // wavefront over (layer, t): 66 stages
    for (int d = 0; d < SEQ + 2; ++d)
        k_stage<<<768, 256, 0, stream>>>(d, xbf, h0, h1, h2,
                                         wih0R, whh0R, wih1R, whh1R, wih2R, whh2R,
                                         b_ih[0], b_hh[0], b_ih[1], b_hh[1], b_ih[2], b_hh[2]);

    const unsigned short* hlast = h2 + (size_t)(SEQ - 1) * (BATCH * HIDDEN);
    k_bn_part<<<16, 1024, 0, stream>>>(hlast, part);
    k_bn_fold<<<HIDDEN / 256, 256, 0, stream>>>(part, gamma, beta, abuf, bbuf);
    k_fc<<<BATCH, 64, 0, stream>>>(hlast, abuf, bbuf, fcW, fcb, (float*)d_out);
}